// Round 12
// baseline (310.021 us; speedup 1.0000x reference)
//
#include <hip/hip_runtime.h>
#include <hip/hip_bf16.h>

using short8 = __attribute__((ext_vector_type(8))) short;
using f32x4  = __attribute__((ext_vector_type(4))) float;

static constexpr int NN = 50000;   // nodes
static constexpr int NE = 800000;  // edges
static constexpr int NBLK = (NN + 255) / 256;  // 196 scan blocks
static constexpr int MPAD = 50048; // 782 * 64 padded rows for bf16 activations
static constexpr int NPART = 8;    // XCD partitions (dst ranges)
static constexpr int PCH = NN / NPART;          // 6250 nodes per partition
static constexpr int NCHB = 200;                // bucket-pass chunks
static constexpr int CHB = NE / NCHB;           // 4000 edges/chunk (exact)
static constexpr int CAP = 131072;              // bucket capacity (mean 100k, ~100 sigma)
static constexpr int PCHK = 8192;               // per-partition read chunk (16 blocks)

__device__ __forceinline__ float clip100(float v) { return fminf(fmaxf(v, -100.f), 100.f); }
__device__ __forceinline__ unsigned short f2b(float v) {
    __hip_bfloat16 h = __float2bfloat16(v);
    return *reinterpret_cast<unsigned short*>(&h);
}
__device__ __forceinline__ float blo(unsigned int u) { return __uint_as_float(u << 16); }
__device__ __forceinline__ float bhi(unsigned int u) { return __uint_as_float(u & 0xFFFF0000u); }
__device__ __forceinline__ float b2f(unsigned short u) {
    return __uint_as_float(((unsigned int)u) << 16);
}

// ---------------- bucketed CSR build ----------------
// Pass 1: chunk -> LDS once; bin edges into 8 dst-partition buckets with
// block-exclusive contiguous runs (one gcur atomic per block x partition).
__global__ __launch_bounds__(256) void k_bucket(const int* __restrict__ idx,
                                                int* __restrict__ ebs,
                                                int* __restrict__ ebd,
                                                int* __restrict__ gcur) {
    __shared__ int ls[CHB], ld[CHB];
    __shared__ int bcnt[8], bbase2[8], bofs[8];
    const int tid = threadIdx.x;
    const int beg = blockIdx.x * CHB;
    for (int i = tid; i < CHB; i += 256) {
        ls[i] = idx[beg + i];
        ld[i] = idx[NE + beg + i];
    }
    if (tid < 8) { bcnt[tid] = 0; bofs[tid] = 0; }
    __syncthreads();
    for (int i = tid; i < CHB; i += 256) atomicAdd(&bcnt[ld[i] / PCH], 1);
    __syncthreads();
    if (tid < 8) bbase2[tid] = atomicAdd(&gcur[tid], bcnt[tid]);
    __syncthreads();
    for (int i = tid; i < CHB; i += 256) {
        const int d = ld[i];
        const int p = d / PCH;
        const int pos = atomicAdd(&bofs[p], 1);
        const int o = p * CAP + bbase2[p] + pos;
        ebs[o] = ls[i];
        ebd[o] = d;
    }
}

// Pass 2: per-node histogram from buckets; partition p touches only its own
// 25 KB cnt slice, reading only its own bucket (XCD-local via blockIdx&7).
__global__ __launch_bounds__(256) void k_histb(const int* __restrict__ ebd,
                                               const int* __restrict__ gcur,
                                               int* __restrict__ cnt) {
    const int p = blockIdx.x & 7;
    const int c = blockIdx.x >> 3;
    const int np = gcur[p];
    const int beg = c * PCHK;
    const int end = min(np, beg + PCHK);
    for (int i = beg + threadIdx.x; i < end; i += 256)
        atomicAdd(&cnt[ebd[p * CAP + i]], 1);
}

// Pass 3 (after scan): fill esrc from buckets; cursor + esrc slices XCD-local.
__global__ __launch_bounds__(256) void k_fillb(const int* __restrict__ ebs,
                                               const int* __restrict__ ebd,
                                               const int* __restrict__ gcur,
                                               int* __restrict__ cur,
                                               int* __restrict__ esrc) {
    const int p = blockIdx.x & 7;
    const int c = blockIdx.x >> 3;
    const int np = gcur[p];
    const int beg = c * PCHK;
    const int end = min(np, beg + PCHK);
    for (int i = beg + threadIdx.x; i < end; i += 256) {
        const int o = p * CAP + i;
        const int d = ebd[o];
        const int pos = atomicAdd(&cur[d], 1);
        esrc[pos] = ebs[o];
    }
}

__global__ __launch_bounds__(256) void k_bsum(const int* __restrict__ cnt,
                                              int* __restrict__ bsum) {
    __shared__ int ls[256];
    const int t = threadIdx.x;
    const int i = blockIdx.x * 256 + t;
    ls[t] = (i < NN) ? cnt[i] : 0;
    __syncthreads();
    for (int off = 128; off > 0; off >>= 1) {
        if (t < off) ls[t] += ls[t + off];
        __syncthreads();
    }
    if (t == 0) bsum[blockIdx.x] = ls[0];
}

__global__ __launch_bounds__(256) void k_scanb(const int* __restrict__ bsum,
                                               int* __restrict__ bbase,
                                               int* __restrict__ rowptr) {
    __shared__ int ls[256];
    const int t = threadIdx.x;
    ls[t] = (t < NBLK) ? bsum[t] : 0;
    __syncthreads();
    for (int off = 1; off < 256; off <<= 1) {
        const int add = (t >= off) ? ls[t - off] : 0;
        __syncthreads();
        ls[t] += add;
        __syncthreads();
    }
    if (t < NBLK) bbase[t] = (t == 0) ? 0 : ls[t - 1];
    if (t == 0) rowptr[NN] = NE;
}

__global__ __launch_bounds__(256) void k_scan2(int* __restrict__ cnt,
                                               const int* __restrict__ bbase,
                                               int* __restrict__ rowptr,
                                               float* __restrict__ dinv) {
    __shared__ int ls[256];
    const int t = threadIdx.x;
    const int i = blockIdx.x * 256 + t;
    const int c = (i < NN) ? cnt[i] : 0;
    ls[t] = c;
    __syncthreads();
    for (int off = 1; off < 256; off <<= 1) {
        const int add = (t >= off) ? ls[t - off] : 0;
        __syncthreads();
        ls[t] += add;
        __syncthreads();
    }
    if (i < NN) {
        const int excl = bbase[blockIdx.x] + ls[t] - c;
        rowptr[i] = excl;
        cnt[i] = excl;  // fill cursor
        dinv[i] = rsqrtf(1.f + (float)c);
    }
}

// ---------------- weight transpose + bf16 convert (+ cnt/gcur zero) ----------
__global__ __launch_bounds__(256) void k_cvtw(const float* __restrict__ W1,
                                              const float* __restrict__ W2,
                                              const float* __restrict__ Wg,
                                              unsigned short* __restrict__ Wt1,
                                              unsigned short* __restrict__ Wt2,
                                              unsigned short* __restrict__ Wgt,
                                              int* __restrict__ cnt,
                                              int* __restrict__ gcur) {
    const int i = blockIdx.x * 256 + threadIdx.x;  // 0..65535
    if (i < NN) cnt[i] = 0;
    if (i < 8) gcur[i] = 0;
    if (i < 16384) {
        const int n = i >> 7, k = i & 127;
        Wt1[i] = f2b(W1[k * 128 + n]);
    } else if (i < 32768) {
        const int j = i - 16384;
        const int n = j >> 7, k = j & 127;
        Wt2[j] = f2b(W2[k * 128 + n]);
    } else {
        const int j = i - 32768;
        const int n = j >> 8, k = j & 255;
        Wgt[j] = f2b(Wg[k * 128 + n]);
    }
}

// ---------------- MFMA GEMM (K=128, LDS-staged Wt) ----------------
template <bool AB16>
__global__ __launch_bounds__(256) void k_mfma_lds(const unsigned short* __restrict__ Ab,
                                                  const float* __restrict__ Af,
                                                  const unsigned short* __restrict__ Wt,
                                                  unsigned short* __restrict__ Cb,
                                                  const float* __restrict__ dinv) {
    __shared__ unsigned short wl[128 * 136];
    const int tid = threadIdx.x;
#pragma unroll
    for (int j = tid; j < 2048; j += 256) {       // 2048 = 128 rows x 16 short8
        const int row = j >> 4, c8 = j & 15;
        *(short8*)(wl + row * 136 + c8 * 8) = *(const short8*)(Wt + row * 128 + c8 * 8);
    }
    __syncthreads();

    const int wv = tid >> 6;
    const int ln = tid & 63;
    const int l16 = ln & 15;
    const int qd = ln >> 4;
    const int rowb = blockIdx.x * 64 + wv * 16;
    const long arow = rowb + l16;
    const int kq = qd * 8;

    f32x4 acc[8];
#pragma unroll
    for (int i = 0; i < 8; ++i) acc[i] = (f32x4){0.f, 0.f, 0.f, 0.f};

#pragma unroll
    for (int kc = 0; kc < 4; ++kc) {
        short8 a;
        if (AB16) {
            a = *(const short8*)(Ab + arow * 128 + kc * 32 + kq);
        } else {
            a = (short8){0, 0, 0, 0, 0, 0, 0, 0};
            if (arow < NN) {
                const float* fp = Af + arow * 128 + kc * 32 + kq;
                const float4 f0 = *(const float4*)fp;
                const float4 f1 = *(const float4*)(fp + 4);
                a[0] = (short)f2b(clip100(f0.x));
                a[1] = (short)f2b(clip100(f0.y));
                a[2] = (short)f2b(clip100(f0.z));
                a[3] = (short)f2b(clip100(f0.w));
                a[4] = (short)f2b(clip100(f1.x));
                a[5] = (short)f2b(clip100(f1.y));
                a[6] = (short)f2b(clip100(f1.z));
                a[7] = (short)f2b(clip100(f1.w));
            }
        }
#pragma unroll
        for (int nt = 0; nt < 8; ++nt) {
            const short8 b = *(const short8*)(wl + (nt * 16 + l16) * 136 + kc * 32 + kq);
            acc[nt] = __builtin_amdgcn_mfma_f32_16x16x32_bf16(a, b, acc[nt], 0, 0, 0);
        }
    }

    const int r0 = rowb + qd * 4;
#pragma unroll
    for (int r = 0; r < 4; ++r) {
        const int row = r0 + r;
        if (row < NN) {
            const float dv = dinv[row];
#pragma unroll
            for (int nt = 0; nt < 8; ++nt) {
                Cb[(long)row * 128 + nt * 16 + l16] = f2b(acc[nt][r] * dv);
            }
        }
    }
}

// ---------------- gate MFMA (K=256, LDS-staged Wgt, write-only epilogue) -----
__global__ __launch_bounds__(256) void k_mfma_gate(const unsigned short* __restrict__ Ab,
                                                   const float* __restrict__ Af,
                                                   const unsigned short* __restrict__ Wt,
                                                   const float* __restrict__ bg,
                                                   float* __restrict__ out) {
    __shared__ unsigned short wl[128 * 264];
    const int tid = threadIdx.x;
#pragma unroll
    for (int j = tid; j < 4096; j += 256) {       // 4096 = 128 rows x 32 short8
        const int row = j >> 5, c8 = j & 31;
        *(short8*)(wl + row * 264 + c8 * 8) = *(const short8*)(Wt + row * 256 + c8 * 8);
    }
    __syncthreads();

    const int wv = tid >> 6;
    const int ln = tid & 63;
    const int l16 = ln & 15;
    const int qd = ln >> 4;
    const int rowb = blockIdx.x * 64 + wv * 16;
    const long arow = rowb + l16;
    const int kq = qd * 8;

    f32x4 acc[8];
#pragma unroll
    for (int i = 0; i < 8; ++i) acc[i] = (f32x4){0.f, 0.f, 0.f, 0.f};

    {
        const unsigned short* ap = Ab + arow * 128 + kq;
#pragma unroll
        for (int kc = 0; kc < 4; ++kc) {
            const short8 a = *(const short8*)(ap + kc * 32);
#pragma unroll
            for (int nt = 0; nt < 8; ++nt) {
                const short8 b = *(const short8*)(wl + (nt * 16 + l16) * 264 + kc * 32 + kq);
                acc[nt] = __builtin_amdgcn_mfma_f32_16x16x32_bf16(a, b, acc[nt], 0, 0, 0);
            }
        }
    }
    {
        const bool valid = arow < NN;
        const float* fp = Af + arow * 128 + kq;
#pragma unroll
        for (int kc = 0; kc < 4; ++kc) {
            short8 a = (short8){0, 0, 0, 0, 0, 0, 0, 0};
            if (valid) {
                const float4 f0 = *(const float4*)(fp + kc * 32);
                const float4 f1 = *(const float4*)(fp + kc * 32 + 4);
                a[0] = (short)f2b(clip100(f0.x));
                a[1] = (short)f2b(clip100(f0.y));
                a[2] = (short)f2b(clip100(f0.z));
                a[3] = (short)f2b(clip100(f0.w));
                a[4] = (short)f2b(clip100(f1.x));
                a[5] = (short)f2b(clip100(f1.y));
                a[6] = (short)f2b(clip100(f1.z));
                a[7] = (short)f2b(clip100(f1.w));
            }
#pragma unroll
            for (int nt = 0; nt < 8; ++nt) {
                const short8 b = *(const short8*)(wl + (nt * 16 + l16) * 264 + 128 + kc * 32 + kq);
                acc[nt] = __builtin_amdgcn_mfma_f32_16x16x32_bf16(a, b, acc[nt], 0, 0, 0);
            }
        }
    }

    const int r0 = rowb + qd * 4;
#pragma unroll
    for (int nt = 0; nt < 8; ++nt) {
        const int col = nt * 16 + l16;
        const float bgv = bg[col];
#pragma unroll
        for (int r = 0; r < 4; ++r) {
            const int row = r0 + r;
            if (row < NN) {
                const float g = 1.f / (1.f + __expf(-(acc[nt][r] + bgv)));
                out[(long)row * 128 + col] = b2f(Ab[(long)row * 128 + col]) * g;
            }
        }
    }
}

// ---------------- fused aggregation (bf16 scaled messages, 4x MLP unroll) ----
template <bool RES>
__global__ __launch_bounds__(256) void k_aggr(const unsigned int* __restrict__ As2,
                                              unsigned short* __restrict__ Bb,
                                              const int* __restrict__ rowptr,
                                              const int* __restrict__ esrc,
                                              const float* __restrict__ dinv,
                                              const float* __restrict__ bias,
                                              const float* __restrict__ x) {
    const int d = (blockIdx.x * 256 + threadIdx.x) >> 6;
    if (d >= NN) return;
    const int lane = threadIdx.x & 63;
    const float dd = dinv[d];

    const unsigned int u = As2[(long)d * 64 + lane];  // self term
    float2 acc;
    acc.x = blo(u);
    acc.y = bhi(u);

    const int beg = rowptr[d];
    const int end = rowptr[d + 1];
    int i = beg;
    for (; i + 4 <= end; i += 4) {
        const int s0 = esrc[i + 0];
        const int s1 = esrc[i + 1];
        const int s2 = esrc[i + 2];
        const int s3 = esrc[i + 3];
        const unsigned int v0 = As2[(long)s0 * 64 + lane];
        const unsigned int v1 = As2[(long)s1 * 64 + lane];
        const unsigned int v2 = As2[(long)s2 * 64 + lane];
        const unsigned int v3 = As2[(long)s3 * 64 + lane];
        acc.x += (blo(v0) + blo(v1)) + (blo(v2) + blo(v3));
        acc.y += (bhi(v0) + bhi(v1)) + (bhi(v2) + bhi(v3));
    }
    for (; i < end; ++i) {
        const unsigned int v = As2[(long)esrc[i] * 64 + lane];
        acc.x += blo(v);
        acc.y += bhi(v);
    }

    const float2 bv = ((const float2*)bias)[lane];
    acc.x = fmaxf(fmaf(acc.x, dd, bv.x), 0.f);
    acc.y = fmaxf(fmaf(acc.y, dd, bv.y), 0.f);
    if (RES) {
        const float2 xv = ((const float2*)x)[(long)d * 64 + lane];
        acc.x += clip100(xv.x);
        acc.y += clip100(xv.y);
    }
    const unsigned int pack = (unsigned int)f2b(acc.x) | ((unsigned int)f2b(acc.y) << 16);
    ((unsigned int*)Bb)[(long)d * 64 + lane] = pack;
}

// ---------------- launch ----------------
extern "C" void kernel_launch(void* const* d_in, const int* in_sizes, int n_in,
                              void* d_out, int out_size, void* d_ws, size_t ws_size,
                              hipStream_t stream) {
    const float* x  = (const float*)d_in[0];
    const int*  eix = (const int*)d_in[1];
    const float* W1 = (const float*)d_in[2];
    const float* b1 = (const float*)d_in[3];
    const float* W2 = (const float*)d_in[4];
    const float* b2 = (const float*)d_in[5];
    const float* Wg = (const float*)d_in[6];
    const float* bg = (const float*)d_in[7];
    float* out = (float*)d_out;

    char* ws = (char*)d_ws;
    unsigned short* As   = (unsigned short*)ws;                     // 12,812,288 B
    unsigned short* hb   = (unsigned short*)(ws + 12812288);        // 12,812,288 B
    unsigned short* Wt1  = (unsigned short*)(ws + 25624576);        // 32,768 B
    unsigned short* Wt2  = (unsigned short*)(ws + 25657344);        // 32,768 B
    unsigned short* Wgt  = (unsigned short*)(ws + 25690112);        // 65,536 B
    int*   cnt    = (int*)(ws + 25755648);                          // 200,704 B
    int*   rowptr = (int*)(ws + 25956352);                          // 200,704 B
    float* dinv   = (float*)(ws + 26157056);                        // 200,704 B
    int*   bsum   = (int*)(ws + 26357760);                          // 4,096 B
    int*   bbase  = (int*)(ws + 26361856);                          // 4,096 B
    int*   gcur   = (int*)(ws + 26365952);                          // 4,096 B
    int*   esrc   = (int*)(ws + 26370048);                          // 3,200,000 B
    int*   ebs    = (int*)(ws + 29570048);                          // 4,194,304 B
    int*   ebd    = (int*)(ws + 33764352);                          // 4,194,304 B
    // end ~37.96 MB

    const int ggrid = MPAD / 64;  // 782
    dim3 blk(256);

    // weight conversion (also zeroes cnt/gcur), then bucketed CSR build
    k_cvtw<<<256, blk, 0, stream>>>(W1, W2, Wg, Wt1, Wt2, Wgt, cnt, gcur);
    k_bucket<<<NCHB, blk, 0, stream>>>(eix, ebs, ebd, gcur);
    k_histb<<<NPART * 16, blk, 0, stream>>>(ebd, gcur, cnt);
    k_bsum<<<NBLK, blk, 0, stream>>>(cnt, bsum);
    k_scanb<<<1, blk, 0, stream>>>(bsum, bbase, rowptr);
    k_scan2<<<NBLK, blk, 0, stream>>>(cnt, bbase, rowptr, dinv);
    k_fillb<<<NPART * 16, blk, 0, stream>>>(ebs, ebd, gcur, cnt, esrc);

    // layer 1: As = bf16((clip(x)@W1) * dinv) ; h1b = bf16(relu(dinv*ΣAs + b1))
    k_mfma_lds<false><<<ggrid, blk, 0, stream>>>(nullptr, x, Wt1, As, dinv);
    k_aggr<false><<<(NN * 64 + 255) / 256, blk, 0, stream>>>(
        (const unsigned int*)As, hb, rowptr, esrc, dinv, b1, nullptr);

    // layer 2: As = bf16((h1b@W2) * dinv) ; hb = bf16(relu(dinv*ΣAs + b2) + clip(x))
    k_mfma_lds<true><<<ggrid, blk, 0, stream>>>(hb, nullptr, Wt2, As, dinv);
    k_aggr<true><<<(NN * 64 + 255) / 256, blk, 0, stream>>>(
        (const unsigned int*)As, hb, rowptr, esrc, dinv, b2, x);

    // gate: G = [hb | clip(x)] @ Wgt (K=256) ; out = b2f(hb) * sigmoid(G + bg)
    k_mfma_gate<<<ggrid, blk, 0, stream>>>(hb, x, Wgt, bg, out);
}

// Round 13
// 232.000 us; speedup vs baseline: 1.3363x; 1.3363x over previous
//
#include <hip/hip_runtime.h>
#include <hip/hip_bf16.h>

using short8 = __attribute__((ext_vector_type(8))) short;
using f32x4  = __attribute__((ext_vector_type(4))) float;

static constexpr int NN = 50000;   // nodes
static constexpr int NE = 800000;  // edges
static constexpr int MPAD = 50048; // 782 * 64 padded rows for bf16 activations
static constexpr int NB2 = 256;    // dst buckets
static constexpr int BNODE = 196;  // nodes per bucket (256*196 = 50176 >= NN)
static constexpr int CAPB = 4096;  // bucket capacity (mean 3125, sigma ~56)
static constexpr int NCHB = 200;   // pass-A chunks
static constexpr int CHB = NE / NCHB;  // 4000 edges per chunk (exact)

__device__ __forceinline__ float clip100(float v) { return fminf(fmaxf(v, -100.f), 100.f); }
__device__ __forceinline__ unsigned short f2b(float v) {
    __hip_bfloat16 h = __float2bfloat16(v);
    return *reinterpret_cast<unsigned short*>(&h);
}
__device__ __forceinline__ float blo(unsigned int u) { return __uint_as_float(u << 16); }
__device__ __forceinline__ float bhi(unsigned int u) { return __uint_as_float(u & 0xFFFF0000u); }
__device__ __forceinline__ float b2f(unsigned short u) {
    return __uint_as_float(((unsigned int)u) << 16);
}

// ---------------- CSR build: 3 kernels, no global per-edge scattered atomics --
// Pass A: chunk -> LDS; 256-bucket histogram; one global atomic per
// block x bucket reserves a contiguous run; scatter (src,dst) int2 pairs.
__global__ __launch_bounds__(256) void k_bucket(const int* __restrict__ idx,
                                                int2* __restrict__ epair,
                                                int* __restrict__ gcur) {
    __shared__ int ls[CHB], ld[CHB];
    __shared__ int bcnt[NB2], bb[NB2], bofs[NB2];
    const int tid = threadIdx.x;
    const int beg = blockIdx.x * CHB;
    for (int i = tid; i < CHB; i += 256) {
        ls[i] = idx[beg + i];
        ld[i] = idx[NE + beg + i];
    }
    bcnt[tid] = 0;
    __syncthreads();
    for (int i = tid; i < CHB; i += 256) atomicAdd(&bcnt[ld[i] / BNODE], 1);
    __syncthreads();
    bb[tid] = atomicAdd(&gcur[tid], bcnt[tid]);
    bofs[tid] = 0;
    __syncthreads();
    for (int i = tid; i < CHB; i += 256) {
        const int d = ld[i];
        const int p = d / BNODE;
        const int pos = atomicAdd(&bofs[p], 1);
        epair[p * CAPB + bb[p] + pos] = make_int2(ls[i], d);
    }
}

// Pass B: exclusive scan of bucket sizes -> global edge base per bucket.
__global__ __launch_bounds__(256) void k_scan256(const int* __restrict__ gcur,
                                                 int* __restrict__ bbase,
                                                 int* __restrict__ rowptr) {
    __shared__ int ls[256];
    const int t = threadIdx.x;
    const int own = gcur[t];
    ls[t] = own;
    __syncthreads();
    for (int off = 1; off < 256; off <<= 1) {
        const int add = (t >= off) ? ls[t - off] : 0;
        __syncthreads();
        ls[t] += add;
        __syncthreads();
    }
    bbase[t] = ls[t] - own;
    if (t == 0) rowptr[NN] = NE;
}

// Pass C: per-bucket LDS counting sort -> coalesced esrc segment + rowptr + dinv.
__global__ __launch_bounds__(256) void k_sortfill(const int2* __restrict__ epair,
                                                  const int* __restrict__ gcur,
                                                  const int* __restrict__ bbase,
                                                  int* __restrict__ rowptr,
                                                  float* __restrict__ dinv,
                                                  int* __restrict__ esrc) {
    __shared__ int ls[CAPB], ld[CAPB], srt[CAPB];
    __shared__ int cntL[256], sc[256], cur[256];
    const int t = threadIdx.x;
    const int b = blockIdx.x;
    const int ne = gcur[b];
    const int base = bbase[b];
    const int nb0 = b * BNODE;
    const int nn = min(NN - nb0, BNODE);
    for (int i = t; i < ne; i += 256) {
        const int2 p = epair[b * CAPB + i];
        ls[i] = p.x;
        ld[i] = p.y - nb0;  // node-local index in [0, nn)
    }
    cntL[t] = 0;
    __syncthreads();
    for (int i = t; i < ne; i += 256) atomicAdd(&cntL[ld[i]], 1);
    __syncthreads();
    sc[t] = cntL[t];
    __syncthreads();
    for (int off = 1; off < 256; off <<= 1) {
        const int add = (t >= off) ? sc[t - off] : 0;
        __syncthreads();
        sc[t] += add;
        __syncthreads();
    }
    const int excl = sc[t] - cntL[t];
    cur[t] = excl;
    if (t < nn) {
        rowptr[nb0 + t] = base + excl;
        dinv[nb0 + t] = rsqrtf(1.f + (float)cntL[t]);
    }
    __syncthreads();
    for (int i = t; i < ne; i += 256) {
        const int pos = atomicAdd(&cur[ld[i]], 1);
        srt[pos] = ls[i];
    }
    __syncthreads();
    for (int i = t; i < ne; i += 256) esrc[base + i] = srt[i];
}

// ---------------- weight transpose + bf16 convert (+ gcur zero) --------------
__global__ __launch_bounds__(256) void k_cvtw(const float* __restrict__ W1,
                                              const float* __restrict__ W2,
                                              const float* __restrict__ Wg,
                                              unsigned short* __restrict__ Wt1,
                                              unsigned short* __restrict__ Wt2,
                                              unsigned short* __restrict__ Wgt,
                                              int* __restrict__ gcur) {
    const int i = blockIdx.x * 256 + threadIdx.x;  // 0..65535
    if (i < NB2) gcur[i] = 0;
    if (i < 16384) {
        const int n = i >> 7, k = i & 127;
        Wt1[i] = f2b(W1[k * 128 + n]);
    } else if (i < 32768) {
        const int j = i - 16384;
        const int n = j >> 7, k = j & 127;
        Wt2[j] = f2b(W2[k * 128 + n]);
    } else {
        const int j = i - 32768;
        const int n = j >> 8, k = j & 255;
        Wgt[j] = f2b(Wg[k * 128 + n]);
    }
}

// ---------------- MFMA GEMM (K=128, LDS-staged Wt) ----------------
template <bool AB16>
__global__ __launch_bounds__(256) void k_mfma_lds(const unsigned short* __restrict__ Ab,
                                                  const float* __restrict__ Af,
                                                  const unsigned short* __restrict__ Wt,
                                                  unsigned short* __restrict__ Cb,
                                                  const float* __restrict__ dinv) {
    __shared__ unsigned short wl[128 * 136];
    const int tid = threadIdx.x;
#pragma unroll
    for (int j = tid; j < 2048; j += 256) {       // 2048 = 128 rows x 16 short8
        const int row = j >> 4, c8 = j & 15;
        *(short8*)(wl + row * 136 + c8 * 8) = *(const short8*)(Wt + row * 128 + c8 * 8);
    }
    __syncthreads();

    const int wv = tid >> 6;
    const int ln = tid & 63;
    const int l16 = ln & 15;
    const int qd = ln >> 4;
    const int rowb = blockIdx.x * 64 + wv * 16;
    const long arow = rowb + l16;
    const int kq = qd * 8;

    f32x4 acc[8];
#pragma unroll
    for (int i = 0; i < 8; ++i) acc[i] = (f32x4){0.f, 0.f, 0.f, 0.f};

#pragma unroll
    for (int kc = 0; kc < 4; ++kc) {
        short8 a;
        if (AB16) {
            a = *(const short8*)(Ab + arow * 128 + kc * 32 + kq);
        } else {
            a = (short8){0, 0, 0, 0, 0, 0, 0, 0};
            if (arow < NN) {
                const float* fp = Af + arow * 128 + kc * 32 + kq;
                const float4 f0 = *(const float4*)fp;
                const float4 f1 = *(const float4*)(fp + 4);
                a[0] = (short)f2b(clip100(f0.x));
                a[1] = (short)f2b(clip100(f0.y));
                a[2] = (short)f2b(clip100(f0.z));
                a[3] = (short)f2b(clip100(f0.w));
                a[4] = (short)f2b(clip100(f1.x));
                a[5] = (short)f2b(clip100(f1.y));
                a[6] = (short)f2b(clip100(f1.z));
                a[7] = (short)f2b(clip100(f1.w));
            }
        }
#pragma unroll
        for (int nt = 0; nt < 8; ++nt) {
            const short8 b = *(const short8*)(wl + (nt * 16 + l16) * 136 + kc * 32 + kq);
            acc[nt] = __builtin_amdgcn_mfma_f32_16x16x32_bf16(a, b, acc[nt], 0, 0, 0);
        }
    }

    const int r0 = rowb + qd * 4;
#pragma unroll
    for (int r = 0; r < 4; ++r) {
        const int row = r0 + r;
        if (row < NN) {
            const float dv = dinv[row];
#pragma unroll
            for (int nt = 0; nt < 8; ++nt) {
                Cb[(long)row * 128 + nt * 16 + l16] = f2b(acc[nt][r] * dv);
            }
        }
    }
}

// ---------------- gate MFMA (K=256, LDS-staged Wgt, write-only epilogue) -----
__global__ __launch_bounds__(256) void k_mfma_gate(const unsigned short* __restrict__ Ab,
                                                   const float* __restrict__ Af,
                                                   const unsigned short* __restrict__ Wt,
                                                   const float* __restrict__ bg,
                                                   float* __restrict__ out) {
    __shared__ unsigned short wl[128 * 264];
    const int tid = threadIdx.x;
#pragma unroll
    for (int j = tid; j < 4096; j += 256) {       // 4096 = 128 rows x 32 short8
        const int row = j >> 5, c8 = j & 31;
        *(short8*)(wl + row * 264 + c8 * 8) = *(const short8*)(Wt + row * 256 + c8 * 8);
    }
    __syncthreads();

    const int wv = tid >> 6;
    const int ln = tid & 63;
    const int l16 = ln & 15;
    const int qd = ln >> 4;
    const int rowb = blockIdx.x * 64 + wv * 16;
    const long arow = rowb + l16;
    const int kq = qd * 8;

    f32x4 acc[8];
#pragma unroll
    for (int i = 0; i < 8; ++i) acc[i] = (f32x4){0.f, 0.f, 0.f, 0.f};

    {
        const unsigned short* ap = Ab + arow * 128 + kq;
#pragma unroll
        for (int kc = 0; kc < 4; ++kc) {
            const short8 a = *(const short8*)(ap + kc * 32);
#pragma unroll
            for (int nt = 0; nt < 8; ++nt) {
                const short8 b = *(const short8*)(wl + (nt * 16 + l16) * 264 + kc * 32 + kq);
                acc[nt] = __builtin_amdgcn_mfma_f32_16x16x32_bf16(a, b, acc[nt], 0, 0, 0);
            }
        }
    }
    {
        const bool valid = arow < NN;
        const float* fp = Af + arow * 128 + kq;
#pragma unroll
        for (int kc = 0; kc < 4; ++kc) {
            short8 a = (short8){0, 0, 0, 0, 0, 0, 0, 0};
            if (valid) {
                const float4 f0 = *(const float4*)(fp + kc * 32);
                const float4 f1 = *(const float4*)(fp + kc * 32 + 4);
                a[0] = (short)f2b(clip100(f0.x));
                a[1] = (short)f2b(clip100(f0.y));
                a[2] = (short)f2b(clip100(f0.z));
                a[3] = (short)f2b(clip100(f0.w));
                a[4] = (short)f2b(clip100(f1.x));
                a[5] = (short)f2b(clip100(f1.y));
                a[6] = (short)f2b(clip100(f1.z));
                a[7] = (short)f2b(clip100(f1.w));
            }
#pragma unroll
            for (int nt = 0; nt < 8; ++nt) {
                const short8 b = *(const short8*)(wl + (nt * 16 + l16) * 264 + 128 + kc * 32 + kq);
                acc[nt] = __builtin_amdgcn_mfma_f32_16x16x32_bf16(a, b, acc[nt], 0, 0, 0);
            }
        }
    }

    const int r0 = rowb + qd * 4;
#pragma unroll
    for (int nt = 0; nt < 8; ++nt) {
        const int col = nt * 16 + l16;
        const float bgv = bg[col];
#pragma unroll
        for (int r = 0; r < 4; ++r) {
            const int row = r0 + r;
            if (row < NN) {
                const float g = 1.f / (1.f + __expf(-(acc[nt][r] + bgv)));
                out[(long)row * 128 + col] = b2f(Ab[(long)row * 128 + col]) * g;
            }
        }
    }
}

// ---------------- fused aggregation (bf16 scaled messages, 8x MLP unroll) ----
template <bool RES>
__global__ __launch_bounds__(256) void k_aggr(const unsigned int* __restrict__ As2,
                                              unsigned short* __restrict__ Bb,
                                              const int* __restrict__ rowptr,
                                              const int* __restrict__ esrc,
                                              const float* __restrict__ dinv,
                                              const float* __restrict__ bias,
                                              const float* __restrict__ x) {
    const int d = (blockIdx.x * 256 + threadIdx.x) >> 6;
    if (d >= NN) return;
    const int lane = threadIdx.x & 63;
    const float dd = dinv[d];

    const unsigned int u = As2[(long)d * 64 + lane];  // self term
    float2 acc;
    acc.x = blo(u);
    acc.y = bhi(u);

    const int beg = rowptr[d];
    const int end = rowptr[d + 1];
    int i = beg;
    for (; i + 8 <= end; i += 8) {
        const int s0 = esrc[i + 0], s1 = esrc[i + 1], s2 = esrc[i + 2], s3 = esrc[i + 3];
        const int s4 = esrc[i + 4], s5 = esrc[i + 5], s6 = esrc[i + 6], s7 = esrc[i + 7];
        const unsigned int v0 = As2[(long)s0 * 64 + lane];
        const unsigned int v1 = As2[(long)s1 * 64 + lane];
        const unsigned int v2 = As2[(long)s2 * 64 + lane];
        const unsigned int v3 = As2[(long)s3 * 64 + lane];
        const unsigned int v4 = As2[(long)s4 * 64 + lane];
        const unsigned int v5 = As2[(long)s5 * 64 + lane];
        const unsigned int v6 = As2[(long)s6 * 64 + lane];
        const unsigned int v7 = As2[(long)s7 * 64 + lane];
        acc.x += ((blo(v0) + blo(v1)) + (blo(v2) + blo(v3))) +
                 ((blo(v4) + blo(v5)) + (blo(v6) + blo(v7)));
        acc.y += ((bhi(v0) + bhi(v1)) + (bhi(v2) + bhi(v3))) +
                 ((bhi(v4) + bhi(v5)) + (bhi(v6) + bhi(v7)));
    }
    if (i + 4 <= end) {
        const int s0 = esrc[i + 0], s1 = esrc[i + 1], s2 = esrc[i + 2], s3 = esrc[i + 3];
        const unsigned int v0 = As2[(long)s0 * 64 + lane];
        const unsigned int v1 = As2[(long)s1 * 64 + lane];
        const unsigned int v2 = As2[(long)s2 * 64 + lane];
        const unsigned int v3 = As2[(long)s3 * 64 + lane];
        acc.x += (blo(v0) + blo(v1)) + (blo(v2) + blo(v3));
        acc.y += (bhi(v0) + bhi(v1)) + (bhi(v2) + bhi(v3));
        i += 4;
    }
    for (; i < end; ++i) {
        const unsigned int v = As2[(long)esrc[i] * 64 + lane];
        acc.x += blo(v);
        acc.y += bhi(v);
    }

    const float2 bv = ((const float2*)bias)[lane];
    acc.x = fmaxf(fmaf(acc.x, dd, bv.x), 0.f);
    acc.y = fmaxf(fmaf(acc.y, dd, bv.y), 0.f);
    if (RES) {
        const float2 xv = ((const float2*)x)[(long)d * 64 + lane];
        acc.x += clip100(xv.x);
        acc.y += clip100(xv.y);
    }
    const unsigned int pack = (unsigned int)f2b(acc.x) | ((unsigned int)f2b(acc.y) << 16);
    ((unsigned int*)Bb)[(long)d * 64 + lane] = pack;
}

// ---------------- launch ----------------
extern "C" void kernel_launch(void* const* d_in, const int* in_sizes, int n_in,
                              void* d_out, int out_size, void* d_ws, size_t ws_size,
                              hipStream_t stream) {
    const float* x  = (const float*)d_in[0];
    const int*  eix = (const int*)d_in[1];
    const float* W1 = (const float*)d_in[2];
    const float* b1 = (const float*)d_in[3];
    const float* W2 = (const float*)d_in[4];
    const float* b2 = (const float*)d_in[5];
    const float* Wg = (const float*)d_in[6];
    const float* bg = (const float*)d_in[7];
    float* out = (float*)d_out;

    char* ws = (char*)d_ws;
    unsigned short* As   = (unsigned short*)ws;                     // 12,812,288 B
    unsigned short* hb   = (unsigned short*)(ws + 12812288);        // 12,812,288 B
    unsigned short* Wt1  = (unsigned short*)(ws + 25624576);        // 32,768 B
    unsigned short* Wt2  = (unsigned short*)(ws + 25657344);        // 32,768 B
    unsigned short* Wgt  = (unsigned short*)(ws + 25690112);        // 65,536 B
    int*   rowptr = (int*)(ws + 25755648);                          // 200,704 B
    float* dinv   = (float*)(ws + 25956352);                        // 200,704 B
    int*   gcur   = (int*)(ws + 26157056);                          // 1,024 B
    int*   bbase  = (int*)(ws + 26158080);                          // 1,024 B
    int*   esrc   = (int*)(ws + 26159104);                          // 3,200,000 B
    int2*  epair  = (int2*)(ws + 29359104);                         // 8,388,608 B
    // end ~37.7 MB

    const int ggrid = MPAD / 64;  // 782
    dim3 blk(256);

    // weight conversion (also zeroes gcur), then 3-kernel CSR build
    k_cvtw<<<256, blk, 0, stream>>>(W1, W2, Wg, Wt1, Wt2, Wgt, gcur);
    k_bucket<<<NCHB, blk, 0, stream>>>(eix, epair, gcur);
    k_scan256<<<1, blk, 0, stream>>>(gcur, bbase, rowptr);
    k_sortfill<<<NB2, blk, 0, stream>>>(epair, gcur, bbase, rowptr, dinv, esrc);

    // layer 1: As = bf16((clip(x)@W1) * dinv) ; h1b = bf16(relu(dinv*ΣAs + b1))
    k_mfma_lds<false><<<ggrid, blk, 0, stream>>>(nullptr, x, Wt1, As, dinv);
    k_aggr<false><<<(NN * 64 + 255) / 256, blk, 0, stream>>>(
        (const unsigned int*)As, hb, rowptr, esrc, dinv, b1, nullptr);

    // layer 2: As = bf16((h1b@W2) * dinv) ; hb = bf16(relu(dinv*ΣAs + b2) + clip(x))
    k_mfma_lds<true><<<ggrid, blk, 0, stream>>>(hb, nullptr, Wt2, As, dinv);
    k_aggr<true><<<(NN * 64 + 255) / 256, blk, 0, stream>>>(
        (const unsigned int*)As, hb, rowptr, esrc, dinv, b2, x);

    // gate: G = [hb | clip(x)] @ Wgt (K=256) ; out = b2f(hb) * sigmoid(G + bg)
    k_mfma_gate<<<ggrid, blk, 0, stream>>>(hb, x, Wgt, bg, out);
}